// Round 2
// baseline (225.978 us; speedup 1.0000x reference)
//
#include <hip/hip_runtime.h>

#define KP 32
#define NQg 16384
#define CD 512
#define HC 256
#define NS 3

typedef __attribute__((ext_vector_type(8))) short short8;
typedef __attribute__((ext_vector_type(4))) short short4_t;
typedef __attribute__((ext_vector_type(8))) __bf16 bf16x8;
typedef __attribute__((ext_vector_type(4))) float floatx4;

union S8B8 { short8 s; bf16x8 b; };

__device__ __forceinline__ short f2bf(float f) {
    union { float f; unsigned u; } v; v.f = f;
    unsigned r = v.u + 0x7fffu + ((v.u >> 16) & 1u);   // RNE
    return (short)(r >> 16);
}
__device__ __forceinline__ float bf2f(short s) {
    union { unsigned u; float f; } v; v.u = ((unsigned)(unsigned short)s) << 16;
    return v.f;
}
__device__ __forceinline__ float bflo(unsigned u) { return __uint_as_float(u << 16); }
__device__ __forceinline__ float bfhi(unsigned u) { return __uint_as_float(u & 0xffff0000u); }

// ================ k_A: softmax | packs | zeros (wmean + acc) | qf->bf16 | hpb ================
__global__ __launch_bounds__(256) void k_A(const float* __restrict__ qd,
                                           const float* __restrict__ W1, const float* __restrict__ W2,
                                           const float* __restrict__ Wc1, const float* __restrict__ proto,
                                           const float* __restrict__ qf, const float* __restrict__ bc1,
                                           short* __restrict__ softT,
                                           short* __restrict__ W1p, short* __restrict__ W2p,
                                           short* __restrict__ wqp,
                                           short* __restrict__ qf2b, float* __restrict__ wmean,
                                           float* __restrict__ accs,
                                           float* __restrict__ hpb,
                                           int* __restrict__ bar, float* __restrict__ dout) {
    int tid = threadIdx.x;
    int bid = blockIdx.x;
    if (bid < 64) {
        int q = bid * 256 + tid;
        float d[32];
        const float4* p = (const float4*)(qd + (size_t)q * 32);
#pragma unroll
        for (int j = 0; j < 8; j++) {
            float4 v = p[j];
            d[4 * j] = v.x; d[4 * j + 1] = v.y; d[4 * j + 2] = v.z; d[4 * j + 3] = v.w;
        }
#pragma unroll
        for (int s = 0; s < 3; s++) {
            float inv = -1.0f / (float)(s + 1);
            float e[32];
            float sum = 0.f;
#pragma unroll
            for (int k = 0; k < 32; k++) { e[k] = __expf(d[k] * inv); sum += e[k]; }
            float r = 1.0f / sum;
#pragma unroll
            for (int k = 0; k < 32; k++)
                softT[(size_t)(s * 32 + k) * NQg + q] = f2bf(e[k] * r);
        }
        return;
    }
    if (bid < 3648) {
        int idx = (bid - 64) * 256 + tid;   // < 917504
        if (idx < 524288) {
            int k = idx >> 9, n = idx & 511;
            W1p[((size_t)(k >> 3) * 512 + n) * 8 + (k & 7)] = f2bf(W1[idx]);
        } else if (idx < 786432) {
            int j = idx - 524288;
            int k = j >> 9, n = j & 511;
            W2p[((size_t)(k >> 3) * 512 + n) * 8 + (k & 7)] = f2bf(W2[j]);
        } else {
            int j = idx - 786432;
            int k = j >> 8, n = j & 255;
            wqp[((size_t)(k >> 3) * 256 + n) * 8 + (k & 7)] = f2bf(Wc1[(size_t)(512 + k) * 256 + n]);
        }
        return;
    }
    if (bid < 4032) {
        if (bid == 3648) {
            if (tid < 32) dout[16384 + tid] = 0.f;
            else if (tid < 40) bar[tid - 32] = 0;
        }
        int idx = (bid - 3648) * 256 + tid;   // < 98304
        if (idx < 49152) wmean[idx] = 0.f;
        else accs[idx - 49152] = 0.f;         // 3 x 16384 step accumulators
        return;
    }
    if (bid < 6080) {
        // cast qf -> bf16: 2048 blocks x 4 coalesced float4-groups per thread
#pragma unroll
        for (int it = 0; it < 4; it++) {
            int j = (bid - 4032) * 1024 + it * 256 + tid;   // < 2,097,152
            float4 v = *(const float4*)&qf[(size_t)j * 4];
            short4_t o;
            o[0] = f2bf(v.x); o[1] = f2bf(v.y); o[2] = f2bf(v.z); o[3] = f2bf(v.w);
            *(short4_t*)&qf2b[(size_t)j * 4] = o;
        }
        return;
    }
    {
        // ---- hpb: 4 independent accumulators + unroll ----
        int r = bid - 6080;
        const float* pr = proto + r * 512;
        const float* wc = Wc1 + tid;
        float a0 = 0.f, a1 = 0.f, a2 = 0.f, a3 = 0.f;
#pragma unroll 4
        for (int i = 0; i < 512; i += 4) {
            float4 p4 = *(const float4*)&pr[i];
            float w0 = wc[(size_t)i * 256];
            float w1 = wc[(size_t)(i + 1) * 256];
            float w2 = wc[(size_t)(i + 2) * 256];
            float w3 = wc[(size_t)(i + 3) * 256];
            a0 += p4.x * w0;
            a1 += p4.y * w1;
            a2 += p4.z * w2;
            a3 += p4.w * w3;
        }
        hpb[r * 256 + tid] = bc1[tid] + ((a0 + a1) + (a2 + a3));
    }
}

// ================ k_B: 0..255 wmean | 256..767 hq (split) | 768..863 wsuminv ================
__global__ __launch_bounds__(256) void k_B(const short* __restrict__ qf2b,
                                           const short* __restrict__ softT,
                                           const short* __restrict__ wqp,
                                           float* __restrict__ wmean,
                                           short* __restrict__ hq_g,
                                           float* __restrict__ wsuminv) {
    __shared__ short B_lds[128 * 40];
    int tid = threadIdx.x;
    int lane = tid & 63, w = tid >> 6;
    int ml = lane & 15, q8 = lane >> 4;

    if (blockIdx.x < 256) {
        int kc = blockIdx.x >> 2, ns = blockIdx.x & 3;
        int c0 = ns * 128;
        int qbase0 = kc * 256;
        int c_l = 2 * lane;
        int q_l = 8 * w;

        floatx4 acc[6][2];
#pragma unroll
        for (int mt = 0; mt < 6; mt++)
#pragma unroll
            for (int nt = 0; nt < 2; nt++) acc[mt][nt] = (floatx4){0.f, 0.f, 0.f, 0.f};

        for (int step = 0; step < 8; step++) {
            int qb = qbase0 + step * 32;
            short8 sA, sB;
#pragma unroll
            for (int i = 0; i < 8; i++) {
                unsigned u = *(const unsigned*)&qf2b[(size_t)(qb + q_l + i) * 512 + c0 + c_l];
                sA[i] = (short)(u & 0xffffu);
                sB[i] = (short)(u >> 16);
            }
            __syncthreads();
            *(short8*)&B_lds[c_l * 40 + q_l] = sA;
            *(short8*)&B_lds[(c_l + 1) * 40 + q_l] = sB;
            S8B8 a[6];
#pragma unroll
            for (int mt = 0; mt < 6; mt++)
                a[mt].s = *(const short8*)&softT[(size_t)(mt * 16 + ml) * NQg + qb + q8 * 8];
            __syncthreads();
#pragma unroll
            for (int nt = 0; nt < 2; nt++) {
                S8B8 b; b.s = *(short8*)&B_lds[(w * 32 + nt * 16 + ml) * 40 + q8 * 8];
#pragma unroll
                for (int mt = 0; mt < 6; mt++)
                    acc[mt][nt] = __builtin_amdgcn_mfma_f32_16x16x32_bf16(a[mt].b, b.b, acc[mt][nt], 0, 0, 0);
            }
        }
#pragma unroll
        for (int mt = 0; mt < 6; mt++) {
#pragma unroll
            for (int nt = 0; nt < 2; nt++) {
                int c = c0 + w * 32 + nt * 16 + ml;
#pragma unroll
                for (int r = 0; r < 4; r++) {
                    int m = mt * 16 + q8 * 4 + r;
                    atomicAdd(&wmean[(size_t)m * 512 + c], acc[mt][nt][r]);
                }
            }
        }
    } else if (blockIdx.x < 768) {
        // hq GEMM: 512 blocks x 32 rows
        int m0 = (blockIdx.x - 256) * 32;
        int n0 = w * 64;
        floatx4 acc[2][4];
#pragma unroll
        for (int mt = 0; mt < 2; mt++)
#pragma unroll
            for (int nt = 0; nt < 4; nt++) acc[mt][nt] = (floatx4){0.f, 0.f, 0.f, 0.f};

#pragma unroll 4
        for (int kc = 0; kc < 512; kc += 32) {
            S8B8 a[2], b[4];
#pragma unroll
            for (int mt = 0; mt < 2; mt++)
                a[mt].s = *(const short8*)&qf2b[(size_t)(m0 + mt * 16 + ml) * 512 + kc + q8 * 8];
#pragma unroll
            for (int nt = 0; nt < 4; nt++)
                b[nt].s = *(const short8*)&wqp[((size_t)((kc >> 3) + q8) * 256 + n0 + nt * 16 + ml) * 8];
#pragma unroll
            for (int mt = 0; mt < 2; mt++)
#pragma unroll
                for (int nt = 0; nt < 4; nt++)
                    acc[mt][nt] = __builtin_amdgcn_mfma_f32_16x16x32_bf16(a[mt].b, b[nt].b, acc[mt][nt], 0, 0, 0);
        }
#pragma unroll
        for (int mt = 0; mt < 2; mt++)
#pragma unroll
            for (int nt = 0; nt < 4; nt++) {
                int col = n0 + nt * 16 + ml;
#pragma unroll
                for (int r = 0; r < 4; r++) {
                    int row = m0 + mt * 16 + q8 * 4 + r;
                    hq_g[(size_t)row * 256 + col] = f2bf(acc[mt][nt][r]);
                }
            }
    } else {
        float* red = (float*)B_lds;   // 256 f, reuse LDS
        int sk = blockIdx.x - 768;
        const short* row = softT + (size_t)sk * NQg;
        float s = 0.f;
#pragma unroll
        for (int j = 0; j < 8; j++) {
            short8 v = *(const short8*)&row[j * 2048 + tid * 8];
#pragma unroll
            for (int i = 0; i < 8; i++) s += bf2f(v[i]);
        }
        red[tid] = s;
        __syncthreads();
        for (int off = 128; off > 0; off >>= 1) {
            if (tid < off) red[tid] += red[tid + off];
            __syncthreads();
        }
        if (tid == 0) wsuminv[sk] = 1.0f / fmaxf(red[0], 1e-6f);
    }
}

// ================ global spin barrier (16 co-resident blocks — PROVEN size, do not widen) ================
__device__ __forceinline__ void gbar(int* bar, int phase, int nblk) {
    __syncthreads();
    if (threadIdx.x == 0) {
        __threadfence();
        __hip_atomic_fetch_add(&bar[phase], 1, __ATOMIC_ACQ_REL, __HIP_MEMORY_SCOPE_AGENT);
        while (__hip_atomic_load(&bar[phase], __ATOMIC_ACQUIRE, __HIP_MEMORY_SCOPE_AGENT) < nblk)
            __builtin_amdgcn_s_sleep(1);
    }
    __syncthreads();
}

// ================ k_D: blocks 0..15 MLP (1 gbar/step, K-split layer-2 via atomics) | 16..1039 confidence ================
__global__ __launch_bounds__(256) void k_D(const float* __restrict__ wmean,
                                           const float* __restrict__ wsuminv,
                                           const short* __restrict__ W1p,
                                           const float* __restrict__ b1,
                                           const short* __restrict__ W2p,
                                           const float* __restrict__ b2,
                                           const float* __restrict__ proto,
                                           float* __restrict__ accs,
                                           int* __restrict__ bar,
                                           const short* __restrict__ hq_g,
                                           const float* __restrict__ hpb,
                                           const float* __restrict__ Wc2,
                                           const float* __restrict__ bc2p,
                                           float* __restrict__ dout) {
    __shared__ float smem[6688];   // 26,752 B
    int tid = threadIdx.x, lane = tid & 63, w = tid >> 6;
    int ml = lane & 15, q8 = lane >> 4;

    if (blockIdx.x < 16) {
        short* hb_s = (short*)smem;            // [32][40] shorts = 2560 B (padded vs bank conflicts)
        float* acc0 = accs;
        float* acc1 = accs + 16384;
        float* acc2 = accs + 32768;
        int nb = blockIdx.x;
        int mh = w >> 1, nh = w & 1;
        int n_loc = nh * 16 + ml;
        int n = nb * 32 + n_loc;
        float b1v = b1[n];
        int arow = mh * 16 + ml;               // this lane's A-row for L1 fragment loads

        const float* pr  = proto + (size_t)arow * 512;
        const float* a0p = acc0 + (size_t)arow * 512;
        const float* a1p = acc1 + (size_t)arow * 512;

#pragma unroll
        for (int s = 0; s < 3; s++) {
            // ---- L1: hb_slice[32, nb*32..+32] = relu(concat(refined_s, wmean_s/wsum) @ W1[:,slice] + b1) ----
            float iv = wsuminv[s * 32 + arow];
            const float* wm = wmean + (size_t)(s * 32 + arow) * 512;
            float sb2 = 0.1f * (float)s;
            floatx4 ac[4];
#pragma unroll
            for (int j = 0; j < 4; j++) ac[j] = (floatx4){0.f, 0.f, 0.f, 0.f};

#pragma unroll
            for (int st = 0; st < 16; st++) {          // K 0..511: refined_s = proto + 0.1*sum(acc_t) + 0.1*s*b2
                int k0 = st * 32 + q8 * 8;
                float f[8];
                float4 pa = *(const float4*)&pr[k0];
                float4 pb = *(const float4*)&pr[k0 + 4];
                f[0] = pa.x; f[1] = pa.y; f[2] = pa.z; f[3] = pa.w;
                f[4] = pb.x; f[5] = pb.y; f[6] = pb.z; f[7] = pb.w;
                if (s >= 1) {
                    float4 qa = *(const float4*)&a0p[k0];
                    float4 qb = *(const float4*)&a0p[k0 + 4];
                    f[0] += 0.1f * qa.x; f[1] += 0.1f * qa.y; f[2] += 0.1f * qa.z; f[3] += 0.1f * qa.w;
                    f[4] += 0.1f * qb.x; f[5] += 0.1f * qb.y; f[6] += 0.1f * qb.z; f[7] += 0.1f * qb.w;
                    float4 ba = *(const float4*)&b2[k0];
                    float4 bb = *(const float4*)&b2[k0 + 4];
                    f[0] += sb2 * ba.x; f[1] += sb2 * ba.y; f[2] += sb2 * ba.z; f[3] += sb2 * ba.w;
                    f[4] += sb2 * bb.x; f[5] += sb2 * bb.y; f[6] += sb2 * bb.z; f[7] += sb2 * bb.w;
                }
                if (s >= 2) {
                    float4 qa = *(const float4*)&a1p[k0];
                    float4 qb = *(const float4*)&a1p[k0 + 4];
                    f[0] += 0.1f * qa.x; f[1] += 0.1f * qa.y; f[2] += 0.1f * qa.z; f[3] += 0.1f * qa.w;
                    f[4] += 0.1f * qb.x; f[5] += 0.1f * qb.y; f[6] += 0.1f * qb.z; f[7] += 0.1f * qb.w;
                }
                short8 t;
#pragma unroll
                for (int i = 0; i < 8; i++) t[i] = f2bf(f[i]);
                S8B8 a; a.s = t;
                S8B8 b; b.s = *(const short8*)&W1p[((size_t)(k0 >> 3) * 512 + n) * 8];
                ac[st & 3] = __builtin_amdgcn_mfma_f32_16x16x32_bf16(a.b, b.b, ac[st & 3], 0, 0, 0);
            }
#pragma unroll
            for (int st = 16; st < 32; st++) {         // K 512..1023: wmean * wsuminv
                int kw = (st - 16) * 32 + q8 * 8;
                float4 wa = *(const float4*)&wm[kw];
                float4 wb = *(const float4*)&wm[kw + 4];
                short8 t;
                t[0] = f2bf(wa.x * iv); t[1] = f2bf(wa.y * iv); t[2] = f2bf(wa.z * iv); t[3] = f2bf(wa.w * iv);
                t[4] = f2bf(wb.x * iv); t[5] = f2bf(wb.y * iv); t[6] = f2bf(wb.z * iv); t[7] = f2bf(wb.w * iv);
                S8B8 a; a.s = t;
                int k0 = st * 32 + q8 * 8;
                S8B8 b; b.s = *(const short8*)&W1p[((size_t)(k0 >> 3) * 512 + n) * 8];
                ac[st & 3] = __builtin_amdgcn_mfma_f32_16x16x32_bf16(a.b, b.b, ac[st & 3], 0, 0, 0);
            }
            floatx4 acf = (ac[0] + ac[1]) + (ac[2] + ac[3]);
#pragma unroll
            for (int r = 0; r < 4; r++)
                hb_s[(mh * 16 + q8 * 4 + r) * 40 + n_loc] = f2bf(fmaxf(acf[r] + b1v, 0.f));
            __syncthreads();

            // ---- L2 K-split partial: acc_s += hb_slice @ W2[nb*32 band, :] (full 32x512 per block) ----
            float* accw = (s == 0) ? acc0 : (s == 1) ? acc1 : acc2;
            S8B8 a2lo, a2hi;
            a2lo.s = *(const short8*)&hb_s[ml * 40 + q8 * 8];
            a2hi.s = *(const short8*)&hb_s[(16 + ml) * 40 + q8 * 8];
#pragma unroll
            for (int nt = 0; nt < 8; nt++) {
                int n2 = w * 128 + nt * 16 + ml;
                S8B8 b; b.s = *(const short8*)&W2p[((size_t)(nb * 4 + q8) * 512 + n2) * 8];
                floatx4 c0 = __builtin_amdgcn_mfma_f32_16x16x32_bf16(a2lo.b, b.b, (floatx4){0.f, 0.f, 0.f, 0.f}, 0, 0, 0);
                floatx4 c1 = __builtin_amdgcn_mfma_f32_16x16x32_bf16(a2hi.b, b.b, (floatx4){0.f, 0.f, 0.f, 0.f}, 0, 0, 0);
#pragma unroll
                for (int r = 0; r < 4; r++) {
                    atomicAdd(&accw[(size_t)(q8 * 4 + r) * 512 + n2], c0[r]);
                    atomicAdd(&accw[(size_t)(16 + q8 * 4 + r) * 512 + n2], c1[r]);
                }
            }
            gbar(bar, s, 16);                  // ONE barrier per step
        }
        // ---- dout = proto + 0.1*(acc0+acc1+acc2) + 0.3*b2 ----
#pragma unroll
        for (int i = 0; i < 4; i++) {
            int idx = nb * 1024 + i * 256 + tid;
            int c = idx & 511;
            dout[idx] = proto[idx] + 0.1f * (acc0[idx] + acc1[idx] + acc2[idx]) + 0.3f * b2[c];
        }
    } else {
        // ---- confidence (verbatim): block = 16q; thread = 2k x 1q ----
        short* hq_lds = (short*)smem;                  // [16][280] s = 8960 B
        short* hp_s   = (short*)smem + 4480;           // [32][260] s = 16640 B
        float* wc2s   = smem + 6400;                   // 256 f
        float* confl  = smem + 6656;                   // 32 f
        int q0 = (blockIdx.x - 16) * 16;

        wc2s[tid] = Wc2[tid];
        if (tid < 32) confl[tid] = 0.f;
#pragma unroll
        for (int i = 0; i < 8; i++) {                  // hp: 2048 float4 -> bf16 short4
            int idx = i * 256 + tid;
            int r = idx >> 6, c = (idx & 63) * 4;
            float4 v = *(const float4*)&hpb[r * 256 + c];
            short4_t o;
            o[0] = f2bf(v.x); o[1] = f2bf(v.y); o[2] = f2bf(v.z); o[3] = f2bf(v.w);
            *(short4_t*)&hp_s[r * 260 + c] = o;
        }
        {
            const short* hqs = hq_g + (size_t)q0 * 256;
            int r = tid >> 4, c = (tid & 15) * 16;
            *(short8*)&hq_lds[r * 280 + c] = *(const short8*)&hqs[r * 256 + c];
            *(short8*)&hq_lds[r * 280 + c + 8] = *(const short8*)&hqs[r * 256 + c + 8];
        }
        __syncthreads();

        int q = tid & 15, kg = tid >> 4;
        int k0 = kg, k1 = kg + 16;
        float s0 = 0.f, s1 = 0.f;
        for (int h = 0; h < 256; h += 4) {
            uint2 hv = *(uint2*)&hq_lds[q * 280 + h];
            float f0 = bflo(hv.x), f1 = bfhi(hv.x), f2 = bflo(hv.y), f3 = bfhi(hv.y);
            uint2 u0 = *(uint2*)&hp_s[k0 * 260 + h];
            uint2 u1 = *(uint2*)&hp_s[k1 * 260 + h];
            float4 wv = *(float4*)&wc2s[h];
            s0 += fmaxf(bflo(u0.x) + f0, 0.f) * wv.x;
            s0 += fmaxf(bfhi(u0.x) + f1, 0.f) * wv.y;
            s0 += fmaxf(bflo(u0.y) + f2, 0.f) * wv.z;
            s0 += fmaxf(bfhi(u0.y) + f3, 0.f) * wv.w;
            s1 += fmaxf(bflo(u1.x) + f0, 0.f) * wv.x;
            s1 += fmaxf(bfhi(u1.x) + f1, 0.f) * wv.y;
            s1 += fmaxf(bflo(u1.y) + f2, 0.f) * wv.z;
            s1 += fmaxf(bfhi(u1.y) + f3, 0.f) * wv.w;
        }
        float bc2 = bc2p[0];
        float v0 = 1.f / (1.f + __expf(-(s0 + bc2)));
        float v1 = 1.f / (1.f + __expf(-(s1 + bc2)));
        atomicAdd(&confl[k0], v0);
        atomicAdd(&confl[k1], v1);
        __syncthreads();
        if (tid < 32) atomicAdd(&dout[16384 + tid], confl[tid] * (1.0f / 16384.0f));
    }
}

extern "C" void kernel_launch(void* const* d_in, const int* in_sizes, int n_in,
                              void* d_out, int out_size, void* d_ws, size_t ws_size,
                              hipStream_t stream) {
    const float* proto = (const float*)d_in[0];
    const float* qf    = (const float*)d_in[1];
    const float* qd    = (const float*)d_in[2];
    const float* W1    = (const float*)d_in[3];
    const float* b1    = (const float*)d_in[4];
    const float* W2    = (const float*)d_in[5];
    const float* b2    = (const float*)d_in[6];
    const float* Wc1   = (const float*)d_in[7];
    const float* bc1   = (const float*)d_in[8];
    const float* Wc2   = (const float*)d_in[9];
    const float* bc2   = (const float*)d_in[10];
    float* out = (float*)d_out;

    float* ws = (float*)d_ws;
    short* softT   = (short*)ws;                 // 1,572,864 s
    short* qf2b    = (short*)(ws + 786432);      // 8,388,608 s
    float* wmean   = ws + 4980736;               // 49,152 f (raw accumulator)
    short* W1p     = (short*)(ws + 5054464);     // 524,288 s
    short* W2p     = (short*)(ws + 5316608);     // 262,144 s
    short* wqp     = (short*)(ws + 5447680);     // 131,072 s
    float* hpb     = ws + 5513216;               // 8,192 f
    int*   bar     = (int*)(ws + 5521408);       // 8 ints
    float* wsuminv = ws + 5521416;               // 96 f
    short* hq      = (short*)(ws + 5521536);     // 4,194,304 s
    float* accs    = ws + 7618688;               // 49,152 f (3 x 32x512 step partials)

    k_A<<<6112, 256, 0, stream>>>(qd, W1, W2, Wc1, proto, qf, bc1, softT, W1p, W2p, wqp,
                                  qf2b, wmean, accs, hpb, bar, out);
    k_B<<<864, 256, 0, stream>>>(qf2b, softT, wqp, wmean, hq, wsuminv);
    k_D<<<1040, 256, 0, stream>>>(wmean, wsuminv, W1p, b1, W2p, b2, proto, accs, bar,
                                  hq, hpb, Wc2, bc2, out);
}

// Round 3
// 180.252 us; speedup vs baseline: 1.2537x; 1.2537x over previous
//
#include <hip/hip_runtime.h>

typedef __attribute__((ext_vector_type(8))) short short8;
typedef __attribute__((ext_vector_type(4))) short short4_t;
typedef __attribute__((ext_vector_type(8))) __bf16 bf16x8;
typedef __attribute__((ext_vector_type(4))) float floatx4;

union S8B8 { short8 s; bf16x8 b; };

__device__ __forceinline__ short f2bf(float f) {
    union { float f; unsigned u; } v; v.f = f;
    unsigned r = v.u + 0x7fffu + ((v.u >> 16) & 1u);   // RNE
    return (short)(r >> 16);
}
__device__ __forceinline__ float bf2f(short s) {
    union { unsigned u; float f; } v; v.u = ((unsigned)(unsigned short)s) << 16;
    return v.f;
}
__device__ __forceinline__ float bflo(unsigned u) { return __uint_as_float(u << 16); }
__device__ __forceinline__ float bfhi(unsigned u) { return __uint_as_float(u & 0xffff0000u); }

// ================ k_A: hpb | coalesced packs | refined init | zeros ================
// packs: one thread = 8 consecutive k for one n -> 8 strided coalesced reads, one 16B write
__global__ __launch_bounds__(256) void k_A(const float* __restrict__ W1, const float* __restrict__ W2,
                                           const float* __restrict__ Wc1, const float* __restrict__ proto,
                                           const float* __restrict__ bc1,
                                           short* __restrict__ W1p, short* __restrict__ W2p,
                                           short* __restrict__ wqp, float* __restrict__ refined,
                                           float* __restrict__ wmean, float* __restrict__ hpb,
                                           int* __restrict__ bar, float* __restrict__ wsum,
                                           float* __restrict__ dout) {
    int tid = threadIdx.x, bid = blockIdx.x;
    if (bid < 32) {
        // ---- hpb: 4 independent accumulators + unroll (proven) ----
        int r = bid;
        const float* pr = proto + r * 512;
        const float* wc = Wc1 + tid;
        float a0 = 0.f, a1 = 0.f, a2 = 0.f, a3 = 0.f;
#pragma unroll 4
        for (int i = 0; i < 512; i += 4) {
            float4 p4 = *(const float4*)&pr[i];
            float w0 = wc[(size_t)i * 256];
            float w1 = wc[(size_t)(i + 1) * 256];
            float w2 = wc[(size_t)(i + 2) * 256];
            float w3 = wc[(size_t)(i + 3) * 256];
            a0 += p4.x * w0;
            a1 += p4.y * w1;
            a2 += p4.z * w2;
            a3 += p4.w * w3;
        }
        hpb[r * 256 + tid] = bc1[tid] + ((a0 + a1) + (a2 + a3));
        return;
    }
    if (bid < 480) {
        int idx = (bid - 32) * 256 + tid;   // < 114688
        if (idx < 65536) {                  // W1 pack: kg 0..127, n 0..511
            int kg = idx >> 9, n = idx & 511;
            short8 o;
#pragma unroll
            for (int j = 0; j < 8; j++) o[j] = f2bf(W1[(size_t)(kg * 8 + j) * 512 + n]);
            *(short8*)&W1p[((size_t)kg * 512 + n) * 8] = o;
        } else if (idx < 98304) {           // W2 pack: kg 0..63, n 0..511
            int j2 = idx - 65536;
            int kg = j2 >> 9, n = j2 & 511;
            short8 o;
#pragma unroll
            for (int j = 0; j < 8; j++) o[j] = f2bf(W2[(size_t)(kg * 8 + j) * 512 + n]);
            *(short8*)&W2p[((size_t)kg * 512 + n) * 8] = o;
        } else {                            // Wc1[512:] pack: kg 0..63, n 0..255
            int j3 = idx - 98304;
            int kg = j3 >> 8, n = j3 & 255;
            short8 o;
#pragma unroll
            for (int j = 0; j < 8; j++) o[j] = f2bf(Wc1[(size_t)(512 + kg * 8 + j) * 256 + n]);
            *(short8*)&wqp[((size_t)kg * 256 + n) * 8] = o;
        }
        return;
    }
    if (bid < 544) {
        int idx = (bid - 480) * 256 + tid;  // < 16384
        refined[idx] = proto[idx];
        return;
    }
    if (bid < 736) {
        int idx = (bid - 544) * 256 + tid;  // < 49152
        wmean[idx] = 0.f;
        return;
    }
    {
        if (tid < 96) wsum[tid] = 0.f;
        else if (tid < 104) bar[tid - 96] = 0;
        else if (tid >= 128 && tid < 160) dout[16384 + tid - 128] = 0.f;
    }
}

// ================ k_B: 256 wmean blocks with in-block softmax (no softT, no qf2b) ================
__global__ __launch_bounds__(256) void k_B(const float* __restrict__ qd, const float* __restrict__ qf,
                                           float* __restrict__ wmean, float* __restrict__ wsum) {
    __shared__ short soft_lds[96 * 264];   // 50,688 B (pad 264: row stride 528B -> ~2-way banks)
    __shared__ short B_lds[128 * 40];      // 10,240 B
    int tid = threadIdx.x;
    int kc = blockIdx.x >> 2, ns = blockIdx.x & 3;
    int qb0 = kc * 256, c0 = ns * 128;

    // ---- phase 1: softmax for this block's 256 q (identical bf16 values to old softT) ----
    {
        float d[32];
        const float4* p = (const float4*)(qd + (size_t)(qb0 + tid) * 32);
#pragma unroll
        for (int j = 0; j < 8; j++) {
            float4 v = p[j];
            d[4 * j] = v.x; d[4 * j + 1] = v.y; d[4 * j + 2] = v.z; d[4 * j + 3] = v.w;
        }
#pragma unroll
        for (int s = 0; s < 3; s++) {
            float inv = -1.0f / (float)(s + 1);
            float e[32];
            float sum = 0.f;
#pragma unroll
            for (int k = 0; k < 32; k++) { e[k] = __expf(d[k] * inv); sum += e[k]; }
            float r = 1.0f / sum;
#pragma unroll
            for (int k = 0; k < 32; k++)
                soft_lds[(s * 32 + k) * 264 + tid] = f2bf(e[k] * r);
        }
    }
    __syncthreads();

    // ---- wsum partials: only ns==0 blocks, rows summed from LDS (same bf16 source as before) ----
    if (ns == 0 && tid < 96) {
        const short* row = &soft_lds[tid * 264];
        float ssum = 0.f;
#pragma unroll 4
        for (int j = 0; j < 32; j++) {
            short8 v = *(const short8*)&row[j * 8];
#pragma unroll
            for (int i = 0; i < 8; i++) ssum += bf2f(v[i]);
        }
        atomicAdd(&wsum[tid], ssum);
    }

    // ---- phase 2: MFMA (R0-verbatim structure; A from LDS, B from qf fp32 inline-cast) ----
    int lane = tid & 63, w = tid >> 6;
    int ml = lane & 15, q8 = lane >> 4;
    int c_l = 2 * lane, q_l = 8 * w;

    floatx4 acc[6][2];
#pragma unroll
    for (int mt = 0; mt < 6; mt++)
#pragma unroll
        for (int nt = 0; nt < 2; nt++) acc[mt][nt] = (floatx4){0.f, 0.f, 0.f, 0.f};

    for (int step = 0; step < 8; step++) {
        int qb = step * 32;
        short8 sA, sB;
#pragma unroll
        for (int i = 0; i < 8; i++) {
            float2 u = *(const float2*)&qf[(size_t)(qb0 + qb + q_l + i) * 512 + c0 + c_l];
            sA[i] = f2bf(u.x);
            sB[i] = f2bf(u.y);
        }
        __syncthreads();
        *(short8*)&B_lds[c_l * 40 + q_l] = sA;
        *(short8*)&B_lds[(c_l + 1) * 40 + q_l] = sB;
        S8B8 a[6];
#pragma unroll
        for (int mt = 0; mt < 6; mt++)
            a[mt].s = *(const short8*)&soft_lds[(mt * 16 + ml) * 264 + qb + q8 * 8];
        __syncthreads();
#pragma unroll
        for (int nt = 0; nt < 2; nt++) {
            S8B8 b; b.s = *(short8*)&B_lds[(w * 32 + nt * 16 + ml) * 40 + q8 * 8];
#pragma unroll
            for (int mt = 0; mt < 6; mt++)
                acc[mt][nt] = __builtin_amdgcn_mfma_f32_16x16x32_bf16(a[mt].b, b.b, acc[mt][nt], 0, 0, 0);
        }
    }
#pragma unroll
    for (int mt = 0; mt < 6; mt++) {
#pragma unroll
        for (int nt = 0; nt < 2; nt++) {
            int c = c0 + w * 32 + nt * 16 + ml;
#pragma unroll
            for (int r = 0; r < 4; r++) {
                int m = mt * 16 + q8 * 4 + r;
                atomicAdd(&wmean[(size_t)m * 512 + c], acc[mt][nt][r]);
            }
        }
    }
}

// ================ global spin barrier (16 co-resident blocks — PROVEN size, do not widen) ================
__device__ __forceinline__ void gbar(int* bar, int phase, int nblk) {
    __syncthreads();
    if (threadIdx.x == 0) {
        __threadfence();
        __hip_atomic_fetch_add(&bar[phase], 1, __ATOMIC_ACQ_REL, __HIP_MEMORY_SCOPE_AGENT);
        while (__hip_atomic_load(&bar[phase], __ATOMIC_ACQUIRE, __HIP_MEMORY_SCOPE_AGENT) < nblk)
            __builtin_amdgcn_s_sleep(1);
    }
    __syncthreads();
}

// ================ k_D: 0..15 fused MLP (R0-proven structure) | 16..1039 confidence w/ in-block hq MFMA ================
__global__ __launch_bounds__(256) void k_D(const float* __restrict__ wmean,
                                           const float* __restrict__ wsum,
                                           const short* __restrict__ W1p,
                                           const float* __restrict__ b1,
                                           const short* __restrict__ W2p,
                                           const float* __restrict__ b2,
                                           float* __restrict__ refined,
                                           short* __restrict__ hb,
                                           int* __restrict__ bar,
                                           const float* __restrict__ qf,
                                           const short* __restrict__ wqp,
                                           const float* __restrict__ hpb,
                                           const float* __restrict__ Wc2,
                                           const float* __restrict__ bc2p,
                                           float* __restrict__ dout) {
    __shared__ float smem[6688];   // 26,752 B
    int tid = threadIdx.x, lane = tid & 63, w = tid >> 6;
    int ml = lane & 15, q8 = lane >> 4;

    if (blockIdx.x < 16) {
        float (*red)[32][36] = (float(*)[32][36])smem;   // 4608 f
        int nb = blockIdx.x;
        int phase = 0;
        for (int s = 0; s < 3; s++) {
            {   // layer 1: hb[:, 32-col slice] = relu(concat @ W1 + b1) bf16
                const float* srcA = (w < 2) ? refined : (wmean + (size_t)s * 32 * 512 - 512);
                float iv0 = 1.f, iv1 = 1.f;
                if (w >= 2) {
                    iv0 = 1.f / fmaxf(wsum[s * 32 + ml], 1e-6f);
                    iv1 = 1.f / fmaxf(wsum[s * 32 + 16 + ml], 1e-6f);
                }
                int kw = w * 256;
                floatx4 acc[2][2];
#pragma unroll
                for (int mt = 0; mt < 2; mt++)
#pragma unroll
                    for (int nt = 0; nt < 2; nt++) acc[mt][nt] = (floatx4){0.f, 0.f, 0.f, 0.f};
                for (int st = 0; st < 8; st++) {
                    int k0 = kw + st * 32 + q8 * 8;
                    S8B8 a[2];
#pragma unroll
                    for (int mt = 0; mt < 2; mt++) {
                        float sc = mt ? iv1 : iv0;
                        const float* p = &srcA[(size_t)(mt * 16 + ml) * 512 + k0];
                        float4 f0 = *(const float4*)p;
                        float4 f1 = *(const float4*)(p + 4);
                        short8 t;
                        t[0] = f2bf(f0.x * sc); t[1] = f2bf(f0.y * sc);
                        t[2] = f2bf(f0.z * sc); t[3] = f2bf(f0.w * sc);
                        t[4] = f2bf(f1.x * sc); t[5] = f2bf(f1.y * sc);
                        t[6] = f2bf(f1.z * sc); t[7] = f2bf(f1.w * sc);
                        a[mt].s = t;
                    }
#pragma unroll
                    for (int nt = 0; nt < 2; nt++) {
                        int n = nb * 32 + nt * 16 + ml;
                        S8B8 b; b.s = *(const short8*)&W1p[((size_t)(k0 >> 3) * 512 + n) * 8];
#pragma unroll
                        for (int mt = 0; mt < 2; mt++)
                            acc[mt][nt] = __builtin_amdgcn_mfma_f32_16x16x32_bf16(a[mt].b, b.b, acc[mt][nt], 0, 0, 0);
                    }
                }
                __syncthreads();
#pragma unroll
                for (int mt = 0; mt < 2; mt++)
#pragma unroll
                    for (int nt = 0; nt < 2; nt++)
#pragma unroll
                        for (int r = 0; r < 4; r++)
                            red[w][mt * 16 + q8 * 4 + r][nt * 16 + ml] = acc[mt][nt][r];
                __syncthreads();
                int m = tid >> 3, n0 = (tid & 7) * 4;
                short4_t o;
#pragma unroll
                for (int i = 0; i < 4; i++) {
                    float v = b1[nb * 32 + n0 + i];
#pragma unroll
                    for (int w4 = 0; w4 < 4; w4++) v += red[w4][m][n0 + i];
                    o[i] = f2bf(fmaxf(v, 0.f));
                }
                *(short4_t*)&hb[(size_t)m * 512 + nb * 32 + n0] = o;
            }
            gbar(bar, phase++, 16);
            {   // layer 2: refined[:, slice] += 0.1*(hb @ W2 + b2)
                int kw = w * 128;
                floatx4 acc[2][2];
#pragma unroll
                for (int mt = 0; mt < 2; mt++)
#pragma unroll
                    for (int nt = 0; nt < 2; nt++) acc[mt][nt] = (floatx4){0.f, 0.f, 0.f, 0.f};
                for (int st = 0; st < 4; st++) {
                    int k0 = kw + st * 32 + q8 * 8;
                    S8B8 a[2];
#pragma unroll
                    for (int mt = 0; mt < 2; mt++)
                        a[mt].s = *(const short8*)&hb[(size_t)(mt * 16 + ml) * 512 + k0];
#pragma unroll
                    for (int nt = 0; nt < 2; nt++) {
                        int n = nb * 32 + nt * 16 + ml;
                        S8B8 b; b.s = *(const short8*)&W2p[((size_t)(k0 >> 3) * 512 + n) * 8];
#pragma unroll
                        for (int mt = 0; mt < 2; mt++)
                            acc[mt][nt] = __builtin_amdgcn_mfma_f32_16x16x32_bf16(a[mt].b, b.b, acc[mt][nt], 0, 0, 0);
                    }
                }
                __syncthreads();
#pragma unroll
                for (int mt = 0; mt < 2; mt++)
#pragma unroll
                    for (int nt = 0; nt < 2; nt++)
#pragma unroll
                        for (int r = 0; r < 4; r++)
                            red[w][mt * 16 + q8 * 4 + r][nt * 16 + ml] = acc[mt][nt][r];
                __syncthreads();
                int m = tid >> 3, n0 = (tid & 7) * 4;
#pragma unroll
                for (int i = 0; i < 4; i++) {
                    int c = nb * 32 + n0 + i;
                    float v = b2[c];
#pragma unroll
                    for (int w4 = 0; w4 < 4; w4++) v += red[w4][m][n0 + i];
                    float val = refined[(size_t)m * 512 + c] + 0.1f * v;
                    refined[(size_t)m * 512 + c] = val;
                    if (s == 2) dout[(size_t)m * 512 + c] = val;
                }
            }
            if (s < 2) gbar(bar, phase++, 16);
        }
    } else {
        // ---- confidence: block = 16q; hq tile computed IN-BLOCK via MFMA (hq array eliminated) ----
        short* hq_lds = (short*)smem;                  // [16][280] s = 8960 B
        short* hp_s   = (short*)smem + 4480;           // [32][260] s = 16640 B
        float* wc2s   = smem + 6400;                   // 256 f
        float* confl  = smem + 6656;                   // 32 f
        int q0 = (blockIdx.x - 16) * 16;

        wc2s[tid] = Wc2[tid];
        if (tid < 32) confl[tid] = 0.f;
#pragma unroll
        for (int i = 0; i < 8; i++) {                  // hp: 2048 float4 -> bf16 short4
            int idx = i * 256 + tid;
            int r = idx >> 6, c = (idx & 63) * 4;
            float4 v = *(const float4*)&hpb[r * 256 + c];
            short4_t o;
            o[0] = f2bf(v.x); o[1] = f2bf(v.y); o[2] = f2bf(v.z); o[3] = f2bf(v.w);
            *(short4_t*)&hp_s[r * 260 + c] = o;
        }
        {   // hq tile: [16 q][256 h] = qf[q0..q0+16] @ wqp, K=512; wave w -> cols w*64..+64
            floatx4 acc[4];
#pragma unroll
            for (int nt = 0; nt < 4; nt++) acc[nt] = (floatx4){0.f, 0.f, 0.f, 0.f};
            const float* qfa = qf + (size_t)(q0 + ml) * 512 + q8 * 8;
#pragma unroll 4
            for (int kc = 0; kc < 512; kc += 32) {
                float4 fa = *(const float4*)&qfa[kc];
                float4 fb = *(const float4*)&qfa[kc + 4];
                short8 t;
                t[0] = f2bf(fa.x); t[1] = f2bf(fa.y); t[2] = f2bf(fa.z); t[3] = f2bf(fa.w);
                t[4] = f2bf(fb.x); t[5] = f2bf(fb.y); t[6] = f2bf(fb.z); t[7] = f2bf(fb.w);
                S8B8 a; a.s = t;
#pragma unroll
                for (int nt = 0; nt < 4; nt++) {
                    int col = w * 64 + nt * 16 + ml;
                    S8B8 b; b.s = *(const short8*)&wqp[((size_t)((kc >> 3) + q8) * 256 + col) * 8];
                    acc[nt] = __builtin_amdgcn_mfma_f32_16x16x32_bf16(a.b, b.b, acc[nt], 0, 0, 0);
                }
            }
#pragma unroll
            for (int nt = 0; nt < 4; nt++)
#pragma unroll
                for (int r = 0; r < 4; r++)
                    hq_lds[(q8 * 4 + r) * 280 + w * 64 + nt * 16 + ml] = f2bf(acc[nt][r]);
        }
        __syncthreads();

        int q = tid & 15, kg = tid >> 4;
        int k0 = kg, k1 = kg + 16;
        float s0 = 0.f, s1 = 0.f;
        for (int h = 0; h < 256; h += 4) {
            uint2 hv = *(uint2*)&hq_lds[q * 280 + h];
            float f0 = bflo(hv.x), f1 = bfhi(hv.x), f2 = bflo(hv.y), f3 = bfhi(hv.y);
            uint2 u0 = *(uint2*)&hp_s[k0 * 260 + h];
            uint2 u1 = *(uint2*)&hp_s[k1 * 260 + h];
            float4 wv = *(float4*)&wc2s[h];
            s0 += fmaxf(bflo(u0.x) + f0, 0.f) * wv.x;
            s0 += fmaxf(bfhi(u0.x) + f1, 0.f) * wv.y;
            s0 += fmaxf(bflo(u0.y) + f2, 0.f) * wv.z;
            s0 += fmaxf(bfhi(u0.y) + f3, 0.f) * wv.w;
            s1 += fmaxf(bflo(u1.x) + f0, 0.f) * wv.x;
            s1 += fmaxf(bfhi(u1.x) + f1, 0.f) * wv.y;
            s1 += fmaxf(bflo(u1.y) + f2, 0.f) * wv.z;
            s1 += fmaxf(bfhi(u1.y) + f3, 0.f) * wv.w;
        }
        float bc2 = bc2p[0];
        float v0 = 1.f / (1.f + __expf(-(s0 + bc2)));
        float v1 = 1.f / (1.f + __expf(-(s1 + bc2)));
        atomicAdd(&confl[k0], v0);
        atomicAdd(&confl[k1], v1);
        __syncthreads();
        if (tid < 32) atomicAdd(&dout[16384 + tid], confl[tid] * (1.0f / 16384.0f));
    }
}

extern "C" void kernel_launch(void* const* d_in, const int* in_sizes, int n_in,
                              void* d_out, int out_size, void* d_ws, size_t ws_size,
                              hipStream_t stream) {
    const float* proto = (const float*)d_in[0];
    const float* qf    = (const float*)d_in[1];
    const float* qd    = (const float*)d_in[2];
    const float* W1    = (const float*)d_in[3];
    const float* b1    = (const float*)d_in[4];
    const float* W2    = (const float*)d_in[5];
    const float* b2    = (const float*)d_in[6];
    const float* Wc1   = (const float*)d_in[7];
    const float* bc1   = (const float*)d_in[8];
    const float* Wc2   = (const float*)d_in[9];
    const float* bc2   = (const float*)d_in[10];
    float* out = (float*)d_out;

    float* ws = (float*)d_ws;
    float* wmean   = ws;                         // 49,152 f (raw accumulator)
    float* refined = ws + 49152;                 // 16,384 f
    short* hb      = (short*)(ws + 65536);       // 16,384 s
    short* W1p     = (short*)(ws + 73728);       // 524,288 s
    short* W2p     = (short*)(ws + 335872);      // 262,144 s
    short* wqp     = (short*)(ws + 466944);      // 131,072 s
    float* hpb     = ws + 532480;                // 8,192 f
    int*   bar     = (int*)(ws + 540672);        // 8 ints
    float* wsum    = ws + 540680;                // 96 f

    k_A<<<737, 256, 0, stream>>>(W1, W2, Wc1, proto, bc1, W1p, W2p, wqp,
                                 refined, wmean, hpb, bar, wsum, out);
    k_B<<<256, 256, 0, stream>>>(qd, qf, wmean, wsum);
    k_D<<<1040, 256, 0, stream>>>(wmean, wsum, W1p, b1, W2p, b2, refined, hb, bar,
                                  qf, wqp, hpb, Wc2, bc2, out);
}